// Round 1
// baseline (32624.139 us; speedup 1.0000x reference)
//
#include <hip/hip_runtime.h>
#include <cfloat>

#define NROWS  32768
#define NCODES 8192
#define DDIM   256

#define MT 128            // rows per block tile
#define NT 128            // codes per block tile
#define BK 8              // D-chunk
#define TM 8              // rows per thread
#define TN 8              // codes per thread
#define KG 4              // K-split groups
#define KPG (NCODES / KG) // 2048 codes per group
#define NTILES (KPG / NT) // 16
#define NCHUNK (DDIM / BK)// 32
#define NTP (NT + (NT / 32) * 4) // 144: +4 floats pad per 32 cols (breaks 4-way b128 conflicts)

__device__ __forceinline__ int bpad(int c) { return c + ((c >> 5) << 2); }

// ---------------- kernel 0: row squared norms ----------------
__global__ __launch_bounds__(256) void row_sq(const float* __restrict__ z,
                                              const float* __restrict__ cb,
                                              float* __restrict__ zsq,
                                              float* __restrict__ esq) {
    const int wave = (blockIdx.x * blockDim.x + threadIdx.x) >> 6; // one wave per row
    const int lane = threadIdx.x & 63;
    if (wave >= NROWS + NCODES) return;
    const float* src;
    float* dst;
    int row;
    if (wave < NROWS) { src = z;  dst = zsq; row = wave; }
    else              { src = cb; dst = esq; row = wave - NROWS; }
    const float4 v = *(const float4*)(src + (size_t)row * DDIM + lane * 4);
    float s = v.x * v.x + v.y * v.y + v.z * v.z + v.w * v.w;
    for (int o = 32; o > 0; o >>= 1) s += __shfl_down(s, o);
    if (lane == 0) dst[row] = s;
}

// ---------------- kernel 1: fused dist-GEMM + partial argmin ----------------
// dist = (z_sq - 2*dot) + e_sq  (same op order / fp32 rounding as the reference)
__global__ __launch_bounds__(256, 4)
void vq_partial(const float* __restrict__ z, const float* __restrict__ cb,
                const float* __restrict__ zsq, const float* __restrict__ esq,
                float* __restrict__ pV, int* __restrict__ pI) {
    __shared__ __align__(16) float As[2][BK][MT];
    __shared__ __align__(16) float Bs[2][BK][NTP];
    __shared__ float zs[MT];
    __shared__ float RedV[MT][17];
    __shared__ int   RedI[MT][17];

    const int b = blockIdx.x;
    const int rt = b >> 2;         // 256 row tiles
    const int kg = b & 3;          // 4 K-groups
    const int rowbase  = rt * MT;
    const int codebase = kg * KPG;

    const int tid = threadIdx.x;
    const int tx = tid & 15;       // col group (8 cols each)
    const int ty = tid >> 4;       // row group (8 rows each)

    if (tid < MT) zs[tid] = zsq[rowbase + tid];

    // staging: each thread loads one float4 of A and one of B per chunk
    const int ldRow = tid >> 1;        // 0..127
    const int ldD   = (tid & 1) << 2;  // 0 or 4
    const int bcw   = bpad(ldRow);     // padded B store column
    const int bcr   = bpad(tx * TN);   // padded B read base

    float bestV[TM];
    int   bestI[TM];
#pragma unroll
    for (int i = 0; i < TM; ++i) { bestV[i] = FLT_MAX; bestI[i] = 0; }

    const float* Aptr = z + (size_t)(rowbase + ldRow) * DDIM + ldD;

    for (int t = 0; t < NTILES; ++t) {
        const int ctile = codebase + t * NT;
        const float* Bptr = cb + (size_t)(ctile + ldRow) * DDIM + ldD;

        float acc[TM][TN];
#pragma unroll
        for (int i = 0; i < TM; ++i)
#pragma unroll
            for (int j = 0; j < TN; ++j) acc[i][j] = 0.f;

        // chunk 0 stage (prior tile's readers are provably past their last
        // use of buf0 — see barrier analysis: last barrier is after chunk 30)
        float4 aReg = *(const float4*)Aptr;
        float4 bReg = *(const float4*)Bptr;
        As[0][ldD + 0][ldRow] = aReg.x; As[0][ldD + 1][ldRow] = aReg.y;
        As[0][ldD + 2][ldRow] = aReg.z; As[0][ldD + 3][ldRow] = aReg.w;
        Bs[0][ldD + 0][bcw] = bReg.x;   Bs[0][ldD + 1][bcw] = bReg.y;
        Bs[0][ldD + 2][bcw] = bReg.z;   Bs[0][ldD + 3][bcw] = bReg.w;
        __syncthreads();

        int buf = 0;
#pragma unroll 2
        for (int c = 0; c < NCHUNK; ++c) {
            float4 aN, bN;
            if (c + 1 < NCHUNK) {  // prefetch next chunk into regs
                aN = *(const float4*)(Aptr + (c + 1) * BK);
                bN = *(const float4*)(Bptr + (c + 1) * BK);
            }
#pragma unroll
            for (int dk = 0; dk < BK; ++dk) {
                const float4 a0 = *(const float4*)&As[buf][dk][ty * TM];
                const float4 a1 = *(const float4*)&As[buf][dk][ty * TM + 4];
                const float4 b0 = *(const float4*)&Bs[buf][dk][bcr];
                const float4 b1 = *(const float4*)&Bs[buf][dk][bcr + 4];
                const float a[TM] = {a0.x, a0.y, a0.z, a0.w, a1.x, a1.y, a1.z, a1.w};
                const float bb[TN] = {b0.x, b0.y, b0.z, b0.w, b1.x, b1.y, b1.z, b1.w};
#pragma unroll
                for (int i = 0; i < TM; ++i)
#pragma unroll
                    for (int j = 0; j < TN; ++j)
                        acc[i][j] = fmaf(a[i], bb[j], acc[i][j]);
            }
            if (c + 1 < NCHUNK) {
                const int nb = buf ^ 1;
                As[nb][ldD + 0][ldRow] = aN.x; As[nb][ldD + 1][ldRow] = aN.y;
                As[nb][ldD + 2][ldRow] = aN.z; As[nb][ldD + 3][ldRow] = aN.w;
                Bs[nb][ldD + 0][bcw] = bN.x;   Bs[nb][ldD + 1][bcw] = bN.y;
                Bs[nb][ldD + 2][bcw] = bN.z;   Bs[nb][ldD + 3][bcw] = bN.w;
                __syncthreads();
                buf = nb;
            }
        }

        // epilogue: scores + running argmin (ascending index order)
        const int cb0 = ctile + tx * TN;
        const float4 e0 = *(const float4*)&esq[cb0];
        const float4 e1 = *(const float4*)&esq[cb0 + 4];
        const float ee[TN] = {e0.x, e0.y, e0.z, e0.w, e1.x, e1.y, e1.z, e1.w};
#pragma unroll
        for (int i = 0; i < TM; ++i) {
            const float zr = zs[ty * TM + i];
#pragma unroll
            for (int j = 0; j < TN; ++j) {
                const float s = (zr - 2.f * acc[i][j]) + ee[j];
                if (s < bestV[i]) { bestV[i] = s; bestI[i] = cb0 + j; } // strict < : first-index tiebreak
            }
        }
    }

    // cross-thread (tx) reduction per row; ascending tx = ascending index
#pragma unroll
    for (int i = 0; i < TM; ++i) {
        RedV[ty * TM + i][tx] = bestV[i];
        RedI[ty * TM + i][tx] = bestI[i];
    }
    __syncthreads();
    if (tid < MT) {
        float v = RedV[tid][0];
        int bi = RedI[tid][0];
        for (int x = 1; x < 16; ++x) {
            const float v2 = RedV[tid][x];
            const int i2 = RedI[tid][x];
            if (v2 < v || (v2 == v && i2 < bi)) { v = v2; bi = i2; }
        }
        const int row = rowbase + tid;
        pV[row * KG + kg] = v;
        pI[row * KG + kg] = bi;
    }
}

// ---------------- kernel 2: finalize argmin, gather, STE out, loss partials ----------------
__global__ __launch_bounds__(256)
void vq_finalize(const float* __restrict__ z, const float* __restrict__ cb,
                 const float* __restrict__ pV, const int* __restrict__ pI,
                 float* __restrict__ out, float* __restrict__ bsum) {
    __shared__ int   sIdx[4];
    __shared__ float sSum[4];
    const int tid = threadIdx.x;
    const int rw = tid >> 6, lane = tid & 63;
    const int row = blockIdx.x * 4 + rw;

    if (lane == 0) {  // combine K-groups in ascending-index order, strict <
        float v = pV[row * KG];
        int bi = pI[row * KG];
        for (int g = 1; g < KG; ++g) {
            const float v2 = pV[row * KG + g];
            if (v2 < v) { v = v2; bi = pI[row * KG + g]; }
        }
        sIdx[rw] = bi;
    }
    __syncthreads();
    const int idx = sIdx[rw];

    const float4 zv = *(const float4*)(z  + (size_t)row * DDIM + lane * 4);
    const float4 ev = *(const float4*)(cb + (size_t)idx * DDIM + lane * 4);
    float4 d, o;
    d.x = ev.x - zv.x; d.y = ev.y - zv.y; d.z = ev.z - zv.z; d.w = ev.w - zv.w;
    o.x = zv.x + d.x;  o.y = zv.y + d.y;  o.z = zv.z + d.z;  o.w = zv.w + d.w; // z + (z_q - z), as reference
    *(float4*)(out + (size_t)row * DDIM + lane * 4) = o;

    float s = d.x * d.x + d.y * d.y + d.z * d.z + d.w * d.w;
    for (int off = 32; off > 0; off >>= 1) s += __shfl_down(s, off);
    if (lane == 0) sSum[rw] = s;
    __syncthreads();
    if (tid == 0) bsum[blockIdx.x] = sSum[0] + sSum[1] + sSum[2] + sSum[3];
}

// ---------------- kernel 3: loss ----------------
__global__ __launch_bounds__(256)
void loss_final(const float* __restrict__ bsum, float* __restrict__ out) {
    __shared__ float red[4];
    const int tid = threadIdx.x;
    float s = 0.f;
    for (int i = tid; i < NROWS / 4; i += 256) s += bsum[i];
    for (int off = 32; off > 0; off >>= 1) s += __shfl_down(s, off);
    const int wv = tid >> 6, lane = tid & 63;
    if (lane == 0) red[wv] = s;
    __syncthreads();
    if (tid == 0) {
        const float tot = red[0] + red[1] + red[2] + red[3];
        // loss = BETA*mse + mse = 1.25 * sum / (N*D)
        out[(size_t)NROWS * DDIM] = tot * (1.25f / (float)((size_t)NROWS * DDIM));
    }
}

extern "C" void kernel_launch(void* const* d_in, const int* in_sizes, int n_in,
                              void* d_out, int out_size, void* d_ws, size_t ws_size,
                              hipStream_t stream) {
    const float* z  = (const float*)d_in[0];
    const float* cb = (const float*)d_in[1];
    float* out = (float*)d_out;

    // workspace carve (~1.25 MB)
    float* zsq  = (float*)d_ws;            // 32768
    float* esq  = zsq + NROWS;             // 8192
    float* pV   = esq + NCODES;            // 32768*4
    int*   pI   = (int*)(pV + NROWS * KG); // 32768*4
    float* bsum = (float*)(pI + NROWS * KG); // 8192

    row_sq<<<(NROWS + NCODES) / 4, 256, 0, stream>>>(z, cb, zsq, esq);
    vq_partial<<<(NROWS / MT) * KG, 256, 0, stream>>>(z, cb, zsq, esq, pV, pI);
    vq_finalize<<<NROWS / 4, 256, 0, stream>>>(z, cb, pV, pI, out, bsum);
    loss_final<<<1, 256, 0, stream>>>(bsum, out);
}

// Round 2
// 2435.851 us; speedup vs baseline: 13.3933x; 13.3933x over previous
//
#include <hip/hip_runtime.h>
#include <cfloat>

#define NROWS  32768
#define NCODES 8192
#define DDIM   256

#define MT 128            // rows per block tile
#define NT 128            // codes per block tile
#define BK 8              // D-chunk
#define TM 8              // rows per thread
#define TN 8              // codes per thread
#define KG 4              // K-split groups
#define KPG (NCODES / KG) // 2048 codes per group
#define NTILES (KPG / NT) // 16
#define NCHUNK (DDIM / BK)// 32
#define NTP (NT + (NT / 32) * 4) // 144: +4 floats pad per 32 cols (breaks 4-way b128 conflicts)

__device__ __forceinline__ int bpad(int c) { return c + ((c >> 5) << 2); }

// ---------------- kernel 0: row squared norms ----------------
__global__ __launch_bounds__(256) void row_sq(const float* __restrict__ z,
                                              const float* __restrict__ cb,
                                              float* __restrict__ zsq,
                                              float* __restrict__ esq) {
    const int wave = (blockIdx.x * blockDim.x + threadIdx.x) >> 6; // one wave per row
    const int lane = threadIdx.x & 63;
    if (wave >= NROWS + NCODES) return;
    const float* src;
    float* dst;
    int row;
    if (wave < NROWS) { src = z;  dst = zsq; row = wave; }
    else              { src = cb; dst = esq; row = wave - NROWS; }
    const float4 v = *(const float4*)(src + (size_t)row * DDIM + lane * 4);
    float s = v.x * v.x + v.y * v.y + v.z * v.z + v.w * v.w;
    for (int o = 32; o > 0; o >>= 1) s += __shfl_down(s, o);
    if (lane == 0) dst[row] = s;
}

// ---------------- kernel 1: fused dist-GEMM + partial argmin ----------------
// dist = (z_sq - 2*dot) + e_sq  (same op order / fp32 rounding as the reference)
// __launch_bounds__(256,1): round-1's (256,4) capped VGPRs at 64 and spilled
// the 64-register accumulator to scratch (75 GB of scratch writes, 33 ms).
__global__ __launch_bounds__(256, 1)
void vq_partial(const float* __restrict__ z, const float* __restrict__ cb,
                const float* __restrict__ zsq, const float* __restrict__ esq,
                float* __restrict__ pV, int* __restrict__ pI) {
    __shared__ __align__(16) float As[2][BK][MT];
    __shared__ __align__(16) float Bs[2][BK][NTP];
    __shared__ float zs[MT];
    __shared__ float RedV[MT][17];
    __shared__ int   RedI[MT][17];

    const int b = blockIdx.x;
    const int rt = b >> 2;         // 256 row tiles
    const int kg = b & 3;          // 4 K-groups
    const int rowbase  = rt * MT;
    const int codebase = kg * KPG;

    const int tid = threadIdx.x;
    const int tx = tid & 15;       // col group (8 cols each)
    const int ty = tid >> 4;       // row group (8 rows each)

    if (tid < MT) zs[tid] = zsq[rowbase + tid];

    // staging: each thread loads one float4 of A and one of B per chunk
    const int ldRow = tid >> 1;        // 0..127
    const int ldD   = (tid & 1) << 2;  // 0 or 4
    const int bcw   = bpad(ldRow);     // padded B store column
    const int bcr   = bpad(tx * TN);   // padded B read base

    float bestV[TM];
    int   bestI[TM];
#pragma unroll
    for (int i = 0; i < TM; ++i) { bestV[i] = FLT_MAX; bestI[i] = 0; }

    const float* Aptr = z + (size_t)(rowbase + ldRow) * DDIM + ldD;

    for (int t = 0; t < NTILES; ++t) {
        const int ctile = codebase + t * NT;
        const float* Bptr = cb + (size_t)(ctile + ldRow) * DDIM + ldD;

        float acc[TM][TN];
#pragma unroll
        for (int i = 0; i < TM; ++i)
#pragma unroll
            for (int j = 0; j < TN; ++j) acc[i][j] = 0.f;

        // chunk 0 stage (prior tile's readers are provably past their last
        // use of buf0: last barrier of prior tile lands after its chunk-30
        // staging, and buf0's last read is chunk 30's compute, before it)
        float4 aReg = *(const float4*)Aptr;
        float4 bReg = *(const float4*)Bptr;
        As[0][ldD + 0][ldRow] = aReg.x; As[0][ldD + 1][ldRow] = aReg.y;
        As[0][ldD + 2][ldRow] = aReg.z; As[0][ldD + 3][ldRow] = aReg.w;
        Bs[0][ldD + 0][bcw] = bReg.x;   Bs[0][ldD + 1][bcw] = bReg.y;
        Bs[0][ldD + 2][bcw] = bReg.z;   Bs[0][ldD + 3][bcw] = bReg.w;
        __syncthreads();

        int buf = 0;
#pragma unroll 2
        for (int c = 0; c < NCHUNK; ++c) {
            float4 aN, bN;
            if (c + 1 < NCHUNK) {  // prefetch next chunk into regs
                aN = *(const float4*)(Aptr + (c + 1) * BK);
                bN = *(const float4*)(Bptr + (c + 1) * BK);
            }
#pragma unroll
            for (int dk = 0; dk < BK; ++dk) {
                const float4 a0 = *(const float4*)&As[buf][dk][ty * TM];
                const float4 a1 = *(const float4*)&As[buf][dk][ty * TM + 4];
                const float4 b0 = *(const float4*)&Bs[buf][dk][bcr];
                const float4 b1 = *(const float4*)&Bs[buf][dk][bcr + 4];
                const float a[TM] = {a0.x, a0.y, a0.z, a0.w, a1.x, a1.y, a1.z, a1.w};
                const float bb[TN] = {b0.x, b0.y, b0.z, b0.w, b1.x, b1.y, b1.z, b1.w};
#pragma unroll
                for (int i = 0; i < TM; ++i)
#pragma unroll
                    for (int j = 0; j < TN; ++j)
                        acc[i][j] = fmaf(a[i], bb[j], acc[i][j]);
            }
            if (c + 1 < NCHUNK) {
                const int nb = buf ^ 1;
                As[nb][ldD + 0][ldRow] = aN.x; As[nb][ldD + 1][ldRow] = aN.y;
                As[nb][ldD + 2][ldRow] = aN.z; As[nb][ldD + 3][ldRow] = aN.w;
                Bs[nb][ldD + 0][bcw] = bN.x;   Bs[nb][ldD + 1][bcw] = bN.y;
                Bs[nb][ldD + 2][bcw] = bN.z;   Bs[nb][ldD + 3][bcw] = bN.w;
                __syncthreads();
                buf = nb;
            }
        }

        // epilogue: scores + running argmin (ascending index order)
        const int cb0 = ctile + tx * TN;
        const float4 e0 = *(const float4*)&esq[cb0];
        const float4 e1 = *(const float4*)&esq[cb0 + 4];
        const float ee[TN] = {e0.x, e0.y, e0.z, e0.w, e1.x, e1.y, e1.z, e1.w};
#pragma unroll
        for (int i = 0; i < TM; ++i) {
            const float zr = zs[ty * TM + i];
#pragma unroll
            for (int j = 0; j < TN; ++j) {
                const float s = (zr - 2.f * acc[i][j]) + ee[j];
                if (s < bestV[i]) { bestV[i] = s; bestI[i] = cb0 + j; } // strict < : first-index tiebreak
            }
        }
    }

    // cross-thread (tx) reduction per row; ascending tx = ascending index
#pragma unroll
    for (int i = 0; i < TM; ++i) {
        RedV[ty * TM + i][tx] = bestV[i];
        RedI[ty * TM + i][tx] = bestI[i];
    }
    __syncthreads();
    if (tid < MT) {
        float v = RedV[tid][0];
        int bi = RedI[tid][0];
        for (int x = 1; x < 16; ++x) {
            const float v2 = RedV[tid][x];
            const int i2 = RedI[tid][x];
            if (v2 < v || (v2 == v && i2 < bi)) { v = v2; bi = i2; }
        }
        const int row = rowbase + tid;
        pV[row * KG + kg] = v;
        pI[row * KG + kg] = bi;
    }
}

// ---------------- kernel 2: finalize argmin, gather, STE out, loss partials ----------------
__global__ __launch_bounds__(256)
void vq_finalize(const float* __restrict__ z, const float* __restrict__ cb,
                 const float* __restrict__ pV, const int* __restrict__ pI,
                 float* __restrict__ out, float* __restrict__ bsum) {
    __shared__ int   sIdx[4];
    __shared__ float sSum[4];
    const int tid = threadIdx.x;
    const int rw = tid >> 6, lane = tid & 63;
    const int row = blockIdx.x * 4 + rw;

    if (lane == 0) {  // combine K-groups in ascending-index order, strict <
        float v = pV[row * KG];
        int bi = pI[row * KG];
        for (int g = 1; g < KG; ++g) {
            const float v2 = pV[row * KG + g];
            if (v2 < v) { v = v2; bi = pI[row * KG + g]; }
        }
        sIdx[rw] = bi;
    }
    __syncthreads();
    const int idx = sIdx[rw];

    const float4 zv = *(const float4*)(z  + (size_t)row * DDIM + lane * 4);
    const float4 ev = *(const float4*)(cb + (size_t)idx * DDIM + lane * 4);
    float4 d, o;
    d.x = ev.x - zv.x; d.y = ev.y - zv.y; d.z = ev.z - zv.z; d.w = ev.w - zv.w;
    o.x = zv.x + d.x;  o.y = zv.y + d.y;  o.z = zv.z + d.z;  o.w = zv.w + d.w; // z + (z_q - z), as reference
    *(float4*)(out + (size_t)row * DDIM + lane * 4) = o;

    float s = d.x * d.x + d.y * d.y + d.z * d.z + d.w * d.w;
    for (int off = 32; off > 0; off >>= 1) s += __shfl_down(s, off);
    if (lane == 0) sSum[rw] = s;
    __syncthreads();
    if (tid == 0) bsum[blockIdx.x] = sSum[0] + sSum[1] + sSum[2] + sSum[3];
}

// ---------------- kernel 3: loss ----------------
__global__ __launch_bounds__(256)
void loss_final(const float* __restrict__ bsum, float* __restrict__ out) {
    __shared__ float red[4];
    const int tid = threadIdx.x;
    float s = 0.f;
    for (int i = tid; i < NROWS / 4; i += 256) s += bsum[i];
    for (int off = 32; off > 0; off >>= 1) s += __shfl_down(s, off);
    const int wv = tid >> 6, lane = tid & 63;
    if (lane == 0) red[wv] = s;
    __syncthreads();
    if (tid == 0) {
        const float tot = red[0] + red[1] + red[2] + red[3];
        // loss = BETA*mse + mse = 1.25 * sum / (N*D)
        out[(size_t)NROWS * DDIM] = tot * (1.25f / (float)((size_t)NROWS * DDIM));
    }
}

extern "C" void kernel_launch(void* const* d_in, const int* in_sizes, int n_in,
                              void* d_out, int out_size, void* d_ws, size_t ws_size,
                              hipStream_t stream) {
    const float* z  = (const float*)d_in[0];
    const float* cb = (const float*)d_in[1];
    float* out = (float*)d_out;

    // workspace carve (~1.25 MB)
    float* zsq  = (float*)d_ws;            // 32768
    float* esq  = zsq + NROWS;             // 8192
    float* pV   = esq + NCODES;            // 32768*4
    int*   pI   = (int*)(pV + NROWS * KG); // 32768*4
    float* bsum = (float*)(pI + NROWS * KG); // 8192

    row_sq<<<(NROWS + NCODES) / 4, 256, 0, stream>>>(z, cb, zsq, esq);
    vq_partial<<<(NROWS / MT) * KG, 256, 0, stream>>>(z, cb, zsq, esq, pV, pI);
    vq_finalize<<<NROWS / 4, 256, 0, stream>>>(z, cb, pV, pI, out, bsum);
    loss_final<<<1, 256, 0, stream>>>(bsum, out);
}

// Round 3
// 592.134 us; speedup vs baseline: 55.0959x; 4.1137x over previous
//
#include <hip/hip_runtime.h>
#include <cfloat>

#define NROWS  32768
#define NCODES 8192
#define DDIM   256
#define KG     4
#define CPB    (NCODES / KG)   // 2048 codes per block
#define NT     128             // codes per code-tile
#define NTILE  (CPB / NT)      // 16
#define BK     32              // k-chunk = one 16x16x32 MFMA k-depth
#define NCH    (DDIM / BK)     // 8 chunks

typedef __attribute__((ext_vector_type(8))) __bf16 bf16x8;
typedef __attribute__((ext_vector_type(4))) float  f32x4;

// ---------------- kernel A: fp32 -> bf16 conversion (z then cb) ----------------
__global__ __launch_bounds__(256)
void convert_bf16(const float* __restrict__ z, const float* __restrict__ cb,
                  __bf16* __restrict__ zb, __bf16* __restrict__ cbb) {
    const size_t i = (size_t)(blockIdx.x * 256 + threadIdx.x) * 8;
    const size_t NZ = (size_t)NROWS * DDIM;
    const float* src; __bf16* dst; size_t off;
    if (i < NZ) { src = z;  dst = zb;  off = i; }
    else        { src = cb; dst = cbb; off = i - NZ; }
    const float4 f0 = *(const float4*)(src + off);
    const float4 f1 = *(const float4*)(src + off + 4);
    bf16x8 v;
    v[0] = (__bf16)f0.x; v[1] = (__bf16)f0.y; v[2] = (__bf16)f0.z; v[3] = (__bf16)f0.w;
    v[4] = (__bf16)f1.x; v[5] = (__bf16)f1.y; v[6] = (__bf16)f1.z; v[7] = (__bf16)f1.w;
    *(bf16x8*)(dst + off) = v;
}

// ---------------- kernel B: codebook row squared norms ----------------
__global__ __launch_bounds__(256)
void code_sq(const float* __restrict__ cb, float* __restrict__ esq) {
    const int wave = (blockIdx.x * 256 + threadIdx.x) >> 6; // one wave per code
    const int lane = threadIdx.x & 63;
    if (wave >= NCODES) return;
    const float4 v = *(const float4*)(cb + (size_t)wave * DDIM + lane * 4);
    float s = v.x * v.x + v.y * v.y + v.z * v.z + v.w * v.w;
    for (int o = 32; o > 0; o >>= 1) s += __shfl_down(s, o);
    if (lane == 0) esq[wave] = s;
}

// ---------------- kernel C: bf16 MFMA distance GEMM + fused argmin ----------------
// score = esq[col] - 2*dot  (zsq is per-row constant -> cancels in argmin)
// LDS layout: per 16-row segment, slot s holds (row seg*16 + (s&15), k-octet s>>4)
// -> global_load_lds lane order == MFMA fragment lane order (A[m=lane&15][k=quad*8+j]).
__global__ __launch_bounds__(256, 1)
void vq_mfma(const __bf16* __restrict__ zb, const __bf16* __restrict__ cbb,
             const float* __restrict__ esq,
             float* __restrict__ pV, int* __restrict__ pI) {
    __shared__ __align__(16) __bf16 Ab[2][128 * BK];  // 8 KB per buffer
    __shared__ __align__(16) __bf16 Bb[2][128 * BK];
    __shared__ float RedV[128][2];
    __shared__ int   RedI[128][2];

    const int b  = blockIdx.x;
    const int rt = b >> 2, kg = b & 3;
    const int rowbase  = rt * 128;
    const int codebase = kg * CPB;

    const int tid = threadIdx.x;
    const int w = tid >> 6, l = tid & 63;
    const int rh = w >> 1, ch = w & 1;     // 2x2 wave grid over 128x128 tile
    const int lm = l & 15, lq = l >> 4;

    const int lane_off = lm * DDIM + lq * 8;  // per-lane global element offset
    const __bf16* Azg = zb + (size_t)rowbase * DDIM + lane_off;

    float bestV[16];
    int   bestI[16];
#pragma unroll
    for (int s = 0; s < 16; ++s) { bestV[s] = FLT_MAX; bestI[s] = 0; }

    f32x4 acc[4][4];

    for (int t = 0; t < NTILE; ++t) {
        const int ct = codebase + t * NT;
        const __bf16* Bzg = cbb + (size_t)ct * DDIM + lane_off;

        // esq prefetch: 4 cols per lane (completes under the MFMAs)
        float ev[4];
#pragma unroll
        for (int fc = 0; fc < 4; ++fc)
            ev[fc] = esq[ct + ch * 64 + fc * 16 + lm];

#pragma unroll
        for (int fr = 0; fr < 4; ++fr)
#pragma unroll
            for (int fc = 0; fc < 4; ++fc)
                acc[fr][fc] = {0.f, 0.f, 0.f, 0.f};

        // stage chunk 0 into buf 0 (wave w stages segments w*4 .. w*4+3)
#pragma unroll
        for (int j = 0; j < 4; ++j) {
            const int g = w * 4 + j;
            if (g < 8)
                __builtin_amdgcn_global_load_lds(
                    (const __attribute__((address_space(1))) void*)(Azg + g * 16 * DDIM),
                    (__attribute__((address_space(3))) void*)&Ab[0][g * 512], 16, 0, 0);
            else
                __builtin_amdgcn_global_load_lds(
                    (const __attribute__((address_space(1))) void*)(Bzg + (g - 8) * 16 * DDIM),
                    (__attribute__((address_space(3))) void*)&Bb[0][(g - 8) * 512], 16, 0, 0);
        }
        __syncthreads();

        int buf = 0;
#pragma unroll
        for (int c = 0; c < NCH; ++c) {
            if (c + 1 < NCH) {  // prefetch next chunk into the other buffer
                const int k0 = (c + 1) * BK;
                const int nb = buf ^ 1;
#pragma unroll
                for (int j = 0; j < 4; ++j) {
                    const int g = w * 4 + j;
                    if (g < 8)
                        __builtin_amdgcn_global_load_lds(
                            (const __attribute__((address_space(1))) void*)(Azg + g * 16 * DDIM + k0),
                            (__attribute__((address_space(3))) void*)&Ab[nb][g * 512], 16, 0, 0);
                    else
                        __builtin_amdgcn_global_load_lds(
                            (const __attribute__((address_space(1))) void*)(Bzg + (g - 8) * 16 * DDIM + k0),
                            (__attribute__((address_space(3))) void*)&Bb[nb][(g - 8) * 512], 16, 0, 0);
                }
            }
            // LDS -> fragments (dense lane-linear ds_read_b128)
            bf16x8 af[4], bfv[4];
#pragma unroll
            for (int fr = 0; fr < 4; ++fr)
                af[fr] = *(const bf16x8*)&Ab[buf][(rh * 4 + fr) * 512 + l * 8];
#pragma unroll
            for (int fc = 0; fc < 4; ++fc)
                bfv[fc] = *(const bf16x8*)&Bb[buf][(ch * 4 + fc) * 512 + l * 8];
#pragma unroll
            for (int fr = 0; fr < 4; ++fr)
#pragma unroll
                for (int fc = 0; fc < 4; ++fc)
                    acc[fr][fc] = __builtin_amdgcn_mfma_f32_16x16x32_bf16(
                        af[fr], bfv[fc], acc[fr][fc], 0, 0, 0);
            __syncthreads();  // staging (vmcnt) drained + all reads of buf done
            buf ^= 1;
        }

        // epilogue: fused argmin update (ascending index order within lane)
#pragma unroll
        for (int fr = 0; fr < 4; ++fr)
#pragma unroll
            for (int fc = 0; fc < 4; ++fc) {
                const int colI = ct + ch * 64 + fc * 16 + lm;
#pragma unroll
                for (int i = 0; i < 4; ++i) {
                    const float s = ev[fc] - 2.f * acc[fr][fc][i];
                    const int slot = fr * 4 + i;
                    if (s < bestV[slot]) { bestV[slot] = s; bestI[slot] = colI; }
                }
            }
    }

    // cross-lane argmin: rows live on the 16 lanes sharing lq; xor-reduce bits 0..3
#pragma unroll
    for (int s = 0; s < 16; ++s) {
#pragma unroll
        for (int m = 1; m < 16; m <<= 1) {
            const float v2 = __shfl_xor(bestV[s], m);
            const int   i2 = __shfl_xor(bestI[s], m);
            if (v2 < bestV[s] || (v2 == bestV[s] && i2 < bestI[s])) {
                bestV[s] = v2; bestI[s] = i2;
            }
        }
    }
    if (lm == 0) {
#pragma unroll
        for (int s = 0; s < 16; ++s) {
            const int rl = rh * 64 + (s >> 2) * 16 + lq * 4 + (s & 3);
            RedV[rl][ch] = bestV[s]; RedI[rl][ch] = bestI[s];
        }
    }
    __syncthreads();
    if (tid < 128) {  // combine the two col-halves; tie -> smaller index
        float v = RedV[tid][0]; int bi = RedI[tid][0];
        const float v2 = RedV[tid][1]; const int i2 = RedI[tid][1];
        if (v2 < v || (v2 == v && i2 < bi)) { v = v2; bi = i2; }
        const int row = rowbase + tid;
        pV[row * KG + kg] = v; pI[row * KG + kg] = bi;
    }
}

// ---------------- kernel D: finalize argmin, gather (fp32), STE out, loss partials ----------------
__global__ __launch_bounds__(256)
void vq_finalize(const float* __restrict__ z, const float* __restrict__ cb,
                 const float* __restrict__ pV, const int* __restrict__ pI,
                 float* __restrict__ out, float* __restrict__ bsum) {
    __shared__ int   sIdx[4];
    __shared__ float sSum[4];
    const int tid = threadIdx.x;
    const int rw = tid >> 6, lane = tid & 63;
    const int row = blockIdx.x * 4 + rw;

    if (lane == 0) {  // combine K-groups; tie -> smaller index (ascending group index)
        float v = pV[row * KG];
        int bi = pI[row * KG];
        for (int g = 1; g < KG; ++g) {
            const float v2 = pV[row * KG + g];
            const int i2 = pI[row * KG + g];
            if (v2 < v || (v2 == v && i2 < bi)) { v = v2; bi = i2; }
        }
        sIdx[rw] = bi;
    }
    __syncthreads();
    const int idx = sIdx[rw];

    const float4 zv = *(const float4*)(z  + (size_t)row * DDIM + lane * 4);
    const float4 ev = *(const float4*)(cb + (size_t)idx * DDIM + lane * 4);
    float4 d, o;
    d.x = ev.x - zv.x; d.y = ev.y - zv.y; d.z = ev.z - zv.z; d.w = ev.w - zv.w;
    o.x = zv.x + d.x;  o.y = zv.y + d.y;  o.z = zv.z + d.z;  o.w = zv.w + d.w;
    *(float4*)(out + (size_t)row * DDIM + lane * 4) = o;

    float s = d.x * d.x + d.y * d.y + d.z * d.z + d.w * d.w;
    for (int off = 32; off > 0; off >>= 1) s += __shfl_down(s, off);
    if (lane == 0) sSum[rw] = s;
    __syncthreads();
    if (tid == 0) bsum[blockIdx.x] = sSum[0] + sSum[1] + sSum[2] + sSum[3];
}

// ---------------- kernel E: loss ----------------
__global__ __launch_bounds__(256)
void loss_final(const float* __restrict__ bsum, float* __restrict__ out) {
    __shared__ float red[4];
    const int tid = threadIdx.x;
    float s = 0.f;
    for (int i = tid; i < NROWS / 4; i += 256) s += bsum[i];
    for (int off = 32; off > 0; off >>= 1) s += __shfl_down(s, off);
    const int wv = tid >> 6, lane = tid & 63;
    if (lane == 0) red[wv] = s;
    __syncthreads();
    if (tid == 0) {
        const float tot = red[0] + red[1] + red[2] + red[3];
        out[(size_t)NROWS * DDIM] = tot * (1.25f / (float)((size_t)NROWS * DDIM));
    }
}

extern "C" void kernel_launch(void* const* d_in, const int* in_sizes, int n_in,
                              void* d_out, int out_size, void* d_ws, size_t ws_size,
                              hipStream_t stream) {
    const float* z  = (const float*)d_in[0];
    const float* cb = (const float*)d_in[1];
    float* out = (float*)d_out;

    // bf16 staging lives inside d_out (33.5 MB); fully overwritten by vq_finalize.
    __bf16* zbf = (__bf16*)d_out;                                // 16 MB
    __bf16* cbf = (__bf16*)d_out + (size_t)NROWS * DDIM;         // 4 MB

    // workspace carve (~1.2 MB)
    float* esq  = (float*)d_ws;               // 8192
    float* pV   = esq + NCODES;               // 32768*4
    int*   pI   = (int*)(pV + NROWS * KG);    // 32768*4
    float* bsum = (float*)(pI + NROWS * KG);  // 8192

    convert_bf16<<<(NROWS + NCODES) * DDIM / 8 / 256, 256, 0, stream>>>(z, cb, zbf, cbf);
    code_sq<<<NCODES / 4, 256, 0, stream>>>(cb, esq);
    vq_mfma<<<(NROWS / 128) * KG, 256, 0, stream>>>(zbf, cbf, esq, pV, pI);
    vq_finalize<<<NROWS / 4, 256, 0, stream>>>(z, cb, pV, pI, out, bsum);
    loss_final<<<1, 256, 0, stream>>>(bsum, out);
}

// Round 4
// 400.588 us; speedup vs baseline: 81.4405x; 1.4782x over previous
//
#include <hip/hip_runtime.h>
#include <cfloat>

#define NROWS  32768
#define NCODES 8192
#define DDIM   256
#define NT     256             // codes per streamed tile
#define NTILE  (NCODES / NT)   // 32
#define BK     32              // k-chunk = one 16x16x32 MFMA k-depth
#define NCH    (DDIM / BK)     // 8 chunks per tile
#define NCHUNKS (NTILE * NCH)  // 256 linear B chunks

typedef __attribute__((ext_vector_type(8))) __bf16 bf16x8;
typedef __attribute__((ext_vector_type(4))) float  f32x4;

// ---------------- kernel A: fp32 -> bf16 conversion (z scaled by -2, cb as-is) ----
// zb = bf16(-2*z): exact power-of-2 scale; lets the MFMA accumulate -2*dot directly.
__global__ __launch_bounds__(256)
void convert_bf16(const float* __restrict__ z, const float* __restrict__ cb,
                  __bf16* __restrict__ zb, __bf16* __restrict__ cbb) {
    const size_t i = (size_t)(blockIdx.x * 256 + threadIdx.x) * 8;
    const size_t NZ = (size_t)NROWS * DDIM;
    const float* src; __bf16* dst; size_t off; float sc;
    if (i < NZ) { src = z;  dst = zb;  off = i;      sc = -2.f; }
    else        { src = cb; dst = cbb; off = i - NZ; sc = 1.f; }
    const float4 f0 = *(const float4*)(src + off);
    const float4 f1 = *(const float4*)(src + off + 4);
    bf16x8 v;
    v[0] = (__bf16)(sc * f0.x); v[1] = (__bf16)(sc * f0.y);
    v[2] = (__bf16)(sc * f0.z); v[3] = (__bf16)(sc * f0.w);
    v[4] = (__bf16)(sc * f1.x); v[5] = (__bf16)(sc * f1.y);
    v[6] = (__bf16)(sc * f1.z); v[7] = (__bf16)(sc * f1.w);
    *(bf16x8*)(dst + off) = v;
}

// ---------------- kernel B: codebook row squared norms ----------------
__global__ __launch_bounds__(256)
void code_sq(const float* __restrict__ cb, float* __restrict__ esq) {
    const int wave = (blockIdx.x * 256 + threadIdx.x) >> 6;
    const int lane = threadIdx.x & 63;
    if (wave >= NCODES) return;
    const float4 v = *(const float4*)(cb + (size_t)wave * DDIM + lane * 4);
    float s = v.x * v.x + v.y * v.y + v.z * v.z + v.w * v.w;
    for (int o = 32; o > 0; o >>= 1) s += __shfl_down(s, o);
    if (lane == 0) esq[wave] = s;
}

// ---------------- kernel C: A-resident bf16 MFMA distance sweep + argmin --------
// Each block: 128 z-rows vs ALL 8192 codes. A (128x256) staged to LDS ONCE.
// B streamed as 256-code x 32-k chunks, double-buffered. score = esq - 2*dot,
// produced directly by MFMA (A pre-scaled by -2, C initialized with esq).
__global__ __launch_bounds__(256, 1)
void vq_mfma(const __bf16* __restrict__ zb, const __bf16* __restrict__ cbb,
             const float* __restrict__ esq, int* __restrict__ pI) {
    __shared__ __align__(16) __bf16 Ab[64 * 512];      // 64 KB: [c*8+g][512]
    __shared__ __align__(16) __bf16 Bb[2][16 * 512];   // 2 x 16 KB
    __shared__ float RedV[128][2];
    __shared__ int   RedI[128][2];

    const int rowbase = blockIdx.x * 128;
    const int tid = threadIdx.x;
    const int w = tid >> 6, l = tid & 63;
    const int rh = w >> 1, ch = w & 1;     // 2x2 wave grid: rows 64, cols 128
    const int lm = l & 15, lq = l >> 4;
    const int lane_off = lm * DDIM + lq * 8;

    // ---- stage A once: 64 (chunk,segment) pieces, wave-strided ----
    for (int j = w; j < 64; j += 4) {
        const int c = j >> 3, g = j & 7;   // j == c*8+g
        __builtin_amdgcn_global_load_lds(
            (const __attribute__((address_space(1))) void*)
                (zb + (size_t)(rowbase + g * 16) * DDIM + c * BK + lane_off),
            (__attribute__((address_space(3))) void*)&Ab[j * 512], 16, 0, 0);
    }
    // ---- stage B chunk 0 (tile 0, k-chunk 0) into Bb[0] ----
#pragma unroll
    for (int j = 0; j < 4; ++j) {
        const int g = w * 4 + j;           // 16 segments of 16 codes
        __builtin_amdgcn_global_load_lds(
            (const __attribute__((address_space(1))) void*)
                (cbb + (size_t)(g * 16) * DDIM + lane_off),
            (__attribute__((address_space(3))) void*)&Bb[0][g * 512], 16, 0, 0);
    }
    // esq for tile 0 (registers, ping-ponged across tiles)
    float evc[8];
#pragma unroll
    for (int fc = 0; fc < 8; ++fc)
        evc[fc] = esq[ch * 128 + fc * 16 + lm];

    float bestV[16];
    int   bestI[16];
#pragma unroll
    for (int s = 0; s < 16; ++s) { bestV[s] = FLT_MAX; bestI[s] = 0; }

    __syncthreads();

    f32x4 acc[4][8];

    for (int t = 0; t < NTILE; ++t) {
        const int ct = t * NT;

        // init acc with esq (C-operand carries the +e_sq term)
#pragma unroll
        for (int fr = 0; fr < 4; ++fr)
#pragma unroll
            for (int fc = 0; fc < 8; ++fc) {
                const float e = evc[fc];
                acc[fr][fc] = (f32x4){e, e, e, e};
            }

        // prefetch next tile's esq (8 chunks of slack before use)
        float evn[8];
        {
            const int tn = (t + 1) & (NTILE - 1);
#pragma unroll
            for (int fc = 0; fc < 8; ++fc)
                evn[fc] = esq[tn * NT + ch * 128 + fc * 16 + lm];
        }

#pragma unroll
        for (int c = 0; c < NCH; ++c) {
            // prefetch linear chunk i = t*8+c+1 into the other buffer
            const int i = t * NCH + c + 1;
            if (i < NCHUNKS) {
                const int nb = (c + 1) & 1;
                const __bf16* Bp = cbb + ((size_t)(i >> 3) << 16) + ((i & 7) << 5) + lane_off;
#pragma unroll
                for (int j = 0; j < 4; ++j) {
                    const int g = w * 4 + j;
                    __builtin_amdgcn_global_load_lds(
                        (const __attribute__((address_space(1))) void*)
                            (Bp + (size_t)(g * 16) * DDIM),
                        (__attribute__((address_space(3))) void*)&Bb[nb][g * 512], 16, 0, 0);
                }
            }
            // fragments (dense lane-linear ds_read_b128, conflict-free)
            const int buf = c & 1;
            bf16x8 af[4], bfv[8];
#pragma unroll
            for (int fr = 0; fr < 4; ++fr)
                af[fr] = *(const bf16x8*)&Ab[(c * 8 + rh * 4 + fr) * 512 + l * 8];
#pragma unroll
            for (int fc = 0; fc < 8; ++fc)
                bfv[fc] = *(const bf16x8*)&Bb[buf][(ch * 8 + fc) * 512 + l * 8];
#pragma unroll
            for (int fr = 0; fr < 4; ++fr)
#pragma unroll
                for (int fc = 0; fc < 8; ++fc)
                    acc[fr][fc] = __builtin_amdgcn_mfma_f32_16x16x32_bf16(
                        af[fr], bfv[fc], acc[fr][fc], 0, 0, 0);
            __syncthreads();   // drain prefetch (vmcnt) + protect Bb[buf] reuse
        }

        // epilogue: fused argmin over this tile (ascending col order)
#pragma unroll
        for (int fr = 0; fr < 4; ++fr)
#pragma unroll
            for (int fc = 0; fc < 8; ++fc) {
                const int colI = ct + ch * 128 + fc * 16 + lm;
#pragma unroll
                for (int i = 0; i < 4; ++i) {
                    const float s = acc[fr][fc][i];
                    const int slot = fr * 4 + i;
                    if (s < bestV[slot]) { bestV[slot] = s; bestI[slot] = colI; }
                }
            }
#pragma unroll
        for (int fc = 0; fc < 8; ++fc) evc[fc] = evn[fc];
    }

    // cross-lane argmin over the 16 col-lanes (bits 0..3 = lm)
#pragma unroll
    for (int s = 0; s < 16; ++s) {
#pragma unroll
        for (int m = 1; m < 16; m <<= 1) {
            const float v2 = __shfl_xor(bestV[s], m);
            const int   i2 = __shfl_xor(bestI[s], m);
            if (v2 < bestV[s] || (v2 == bestV[s] && i2 < bestI[s])) {
                bestV[s] = v2; bestI[s] = i2;
            }
        }
    }
    if (lm == 0) {
#pragma unroll
        for (int s = 0; s < 16; ++s) {
            const int rl = rh * 64 + (s >> 2) * 16 + lq * 4 + (s & 3);
            RedV[rl][ch] = bestV[s]; RedI[rl][ch] = bestI[s];
        }
    }
    __syncthreads();
    if (tid < 128) {  // combine the two col-halves; tie -> smaller index
        float v = RedV[tid][0]; int bi = RedI[tid][0];
        const float v2 = RedV[tid][1]; const int i2 = RedI[tid][1];
        if (v2 < v || (v2 == v && i2 < bi)) { v = v2; bi = i2; }
        pI[rowbase + tid] = bi;
    }
}

// ---------------- kernel D: gather (fp32), STE out, loss partials ----------------
__global__ __launch_bounds__(256)
void vq_finalize(const float* __restrict__ z, const float* __restrict__ cb,
                 const int* __restrict__ pI,
                 float* __restrict__ out, float* __restrict__ bsum) {
    __shared__ float sSum[4];
    const int tid = threadIdx.x;
    const int rw = tid >> 6, lane = tid & 63;
    const int row = blockIdx.x * 4 + rw;
    const int idx = pI[row];

    const float4 zv = *(const float4*)(z  + (size_t)row * DDIM + lane * 4);
    const float4 ev = *(const float4*)(cb + (size_t)idx * DDIM + lane * 4);
    float4 d, o;
    d.x = ev.x - zv.x; d.y = ev.y - zv.y; d.z = ev.z - zv.z; d.w = ev.w - zv.w;
    o.x = zv.x + d.x;  o.y = zv.y + d.y;  o.z = zv.z + d.z;  o.w = zv.w + d.w;
    *(float4*)(out + (size_t)row * DDIM + lane * 4) = o;

    float s = d.x * d.x + d.y * d.y + d.z * d.z + d.w * d.w;
    for (int off = 32; off > 0; off >>= 1) s += __shfl_down(s, off);
    if (lane == 0) sSum[rw] = s;
    __syncthreads();
    if (tid == 0) bsum[blockIdx.x] = sSum[0] + sSum[1] + sSum[2] + sSum[3];
}

// ---------------- kernel E: loss ----------------
__global__ __launch_bounds__(256)
void loss_final(const float* __restrict__ bsum, float* __restrict__ out) {
    __shared__ float red[4];
    const int tid = threadIdx.x;
    float s = 0.f;
    for (int i = tid; i < NROWS / 4; i += 256) s += bsum[i];
    for (int off = 32; off > 0; off >>= 1) s += __shfl_down(s, off);
    const int wv = tid >> 6, lane = tid & 63;
    if (lane == 0) red[wv] = s;
    __syncthreads();
    if (tid == 0) {
        const float tot = red[0] + red[1] + red[2] + red[3];
        out[(size_t)NROWS * DDIM] = tot * (1.25f / (float)((size_t)NROWS * DDIM));
    }
}

extern "C" void kernel_launch(void* const* d_in, const int* in_sizes, int n_in,
                              void* d_out, int out_size, void* d_ws, size_t ws_size,
                              hipStream_t stream) {
    const float* z  = (const float*)d_in[0];
    const float* cb = (const float*)d_in[1];
    float* out = (float*)d_out;

    // bf16 staging inside d_out (fully overwritten by vq_finalize afterwards)
    __bf16* zbf = (__bf16*)d_out;                           // 16 MB (holds -2z)
    __bf16* cbf = (__bf16*)d_out + (size_t)NROWS * DDIM;    // 4 MB

    // workspace carve (~200 KB)
    float* esq  = (float*)d_ws;               // 8192
    int*   pI   = (int*)(esq + NCODES);       // 32768
    float* bsum = (float*)(pI + NROWS);       // 8192

    convert_bf16<<<(NROWS + NCODES) * DDIM / 8 / 256, 256, 0, stream>>>(z, cb, zbf, cbf);
    code_sq<<<NCODES / 4, 256, 0, stream>>>(cb, esq);
    vq_mfma<<<NROWS / 128, 256, 0, stream>>>(zbf, cbf, esq, pI);
    vq_finalize<<<NROWS / 4, 256, 0, stream>>>(z, cb, pI, out, bsum);
    loss_final<<<1, 256, 0, stream>>>(bsum, out);
}

// Round 5
// 328.604 us; speedup vs baseline: 99.2809x; 1.2191x over previous
//
#include <hip/hip_runtime.h>
#include <cfloat>

#define NROWS  32768
#define NCODES 8192
#define DDIM   256
#define NT     256             // codes per streamed tile
#define NTILE  (NCODES / NT)   // 32
#define BK     32              // k-chunk = one 16x16x32 MFMA k-depth
#define NCH    (DDIM / BK)     // 8 chunks per tile
#define NCHUNKS (NTILE * NCH)  // 256 linear B chunks

typedef __attribute__((ext_vector_type(8))) __bf16 bf16x8;
typedef __attribute__((ext_vector_type(4))) float  f32x4;

// ---- kernel A: fp32 -> bf16 (z scaled by -2 exactly; cb as-is) + fused esq ----
// Block-aligned split: z region = 4096 blocks, cb region = 1024 blocks.
// cb blocks also reduce row squared-norms (32 threads == 1 row of 256).
__global__ __launch_bounds__(256)
void convert_bf16(const float* __restrict__ z, const float* __restrict__ cb,
                  __bf16* __restrict__ zb, __bf16* __restrict__ cbb,
                  float* __restrict__ esq) {
    const size_t i = (size_t)(blockIdx.x * 256 + threadIdx.x) * 8;
    const size_t NZ = (size_t)NROWS * DDIM;
    if (i < NZ) {
        const float4 f0 = *(const float4*)(z + i);
        const float4 f1 = *(const float4*)(z + i + 4);
        bf16x8 v;
        v[0] = (__bf16)(-2.f * f0.x); v[1] = (__bf16)(-2.f * f0.y);
        v[2] = (__bf16)(-2.f * f0.z); v[3] = (__bf16)(-2.f * f0.w);
        v[4] = (__bf16)(-2.f * f1.x); v[5] = (__bf16)(-2.f * f1.y);
        v[6] = (__bf16)(-2.f * f1.z); v[7] = (__bf16)(-2.f * f1.w);
        *(bf16x8*)(zb + i) = v;
    } else {
        const size_t off = i - NZ;
        const float4 f0 = *(const float4*)(cb + off);
        const float4 f1 = *(const float4*)(cb + off + 4);
        bf16x8 v;
        v[0] = (__bf16)f0.x; v[1] = (__bf16)f0.y; v[2] = (__bf16)f0.z; v[3] = (__bf16)f0.w;
        v[4] = (__bf16)f1.x; v[5] = (__bf16)f1.y; v[6] = (__bf16)f1.z; v[7] = (__bf16)f1.w;
        *(bf16x8*)(cbb + off) = v;
        float s = f0.x * f0.x + f0.y * f0.y + f0.z * f0.z + f0.w * f0.w
                + f1.x * f1.x + f1.y * f1.y + f1.z * f1.z + f1.w * f1.w;
        for (int o = 16; o > 0; o >>= 1) s += __shfl_down(s, o, 32);
        if ((threadIdx.x & 31) == 0) esq[off >> 8] = s;
    }
}

// ---- kernel B: A-resident bf16 MFMA distance sweep + fused argmin ----
// 512 threads / 8 waves (2 per SIMD for latency hiding — round 4's 4-wave
// version exposed every ds_read/vmcnt stall: MfmaUtil 18%).
// Block: 128 z-rows vs ALL 8192 codes. A (128x256) in LDS once; B streamed
// 256-code x 32-k chunks, double-buffered. Wave tile 64x64.
// score = esq - 2*dot via MFMA directly (A pre-scaled, C init = esq).
__global__ __launch_bounds__(512)
void vq_mfma(const __bf16* __restrict__ zb, const __bf16* __restrict__ cbb,
             const float* __restrict__ esq, int* __restrict__ pI) {
    __shared__ __align__(16) __bf16 Ab[64 * 512];      // 64 KB: [c*8+g][512]
    __shared__ __align__(16) __bf16 Bb[2][16 * 512];   // 2 x 16 KB
    __shared__ float RedV[128][4];
    __shared__ int   RedI[128][4];

    const int rowbase = blockIdx.x * 128;
    const int tid = threadIdx.x;
    const int w = tid >> 6, l = tid & 63;
    const int rh = w >> 2, ch = w & 3;     // 2x4 wave grid: 64-row x 64-col tiles
    const int lm = l & 15, lq = l >> 4;
    const int lane_off = lm * DDIM + lq * 8;

    // ---- stage A once: 64 (chunk,segment) pieces, wave-strided ----
    for (int j = w; j < 64; j += 8) {
        const int c = j >> 3, g = j & 7;   // j == c*8+g
        __builtin_amdgcn_global_load_lds(
            (const __attribute__((address_space(1))) void*)
                (zb + (size_t)(rowbase + g * 16) * DDIM + c * BK + lane_off),
            (__attribute__((address_space(3))) void*)&Ab[j * 512], 16, 0, 0);
    }
    // ---- stage B chunk 0 into Bb[0]: 16 segments, 2 per wave ----
#pragma unroll
    for (int j = 0; j < 2; ++j) {
        const int g = w * 2 + j;
        __builtin_amdgcn_global_load_lds(
            (const __attribute__((address_space(1))) void*)
                (cbb + (size_t)(g * 16) * DDIM + lane_off),
            (__attribute__((address_space(3))) void*)&Bb[0][g * 512], 16, 0, 0);
    }
    // esq for tile 0 (registers, ping-ponged across tiles)
    float evc[4];
#pragma unroll
    for (int fc = 0; fc < 4; ++fc)
        evc[fc] = esq[ch * 64 + fc * 16 + lm];

    float bestV[16];
    int   bestI[16];
#pragma unroll
    for (int s = 0; s < 16; ++s) { bestV[s] = FLT_MAX; bestI[s] = 0; }

    __syncthreads();

    f32x4 acc[4][4];

    for (int t = 0; t < NTILE; ++t) {
        const int ct = t * NT;

        // init acc with esq (C-operand carries the +e_sq term)
#pragma unroll
        for (int fr = 0; fr < 4; ++fr)
#pragma unroll
            for (int fc = 0; fc < 4; ++fc) {
                const float e = evc[fc];
                acc[fr][fc] = (f32x4){e, e, e, e};
            }

        // prefetch next tile's esq (8 chunks of slack before use)
        float evn[4];
        {
            const int tn = (t + 1) & (NTILE - 1);
#pragma unroll
            for (int fc = 0; fc < 4; ++fc)
                evn[fc] = esq[tn * NT + ch * 64 + fc * 16 + lm];
        }

#pragma unroll
        for (int c = 0; c < NCH; ++c) {
            // prefetch linear chunk i = t*8+c+1 into the other buffer
            const int i = t * NCH + c + 1;
            if (i < NCHUNKS) {
                const int nb = (c + 1) & 1;
                const __bf16* Bp = cbb + ((size_t)(i >> 3) << 16) + ((i & 7) << 5) + lane_off;
#pragma unroll
                for (int j = 0; j < 2; ++j) {
                    const int g = w * 2 + j;
                    __builtin_amdgcn_global_load_lds(
                        (const __attribute__((address_space(1))) void*)
                            (Bp + (size_t)(g * 16) * DDIM),
                        (__attribute__((address_space(3))) void*)&Bb[nb][g * 512], 16, 0, 0);
                }
            }
            // fragments (dense lane-linear ds_read_b128, conflict-free)
            const int buf = c & 1;
            bf16x8 af[4], bfv[4];
#pragma unroll
            for (int fr = 0; fr < 4; ++fr)
                af[fr] = *(const bf16x8*)&Ab[(c * 8 + rh * 4 + fr) * 512 + l * 8];
#pragma unroll
            for (int fc = 0; fc < 4; ++fc)
                bfv[fc] = *(const bf16x8*)&Bb[buf][(ch * 4 + fc) * 512 + l * 8];
#pragma unroll
            for (int fr = 0; fr < 4; ++fr)
#pragma unroll
                for (int fc = 0; fc < 4; ++fc)
                    acc[fr][fc] = __builtin_amdgcn_mfma_f32_16x16x32_bf16(
                        af[fr], bfv[fc], acc[fr][fc], 0, 0, 0);
            __syncthreads();   // drain prefetch (vmcnt) + protect Bb[buf] reuse
        }

        // epilogue: fused argmin over this tile (ascending col order)
#pragma unroll
        for (int fr = 0; fr < 4; ++fr)
#pragma unroll
            for (int fc = 0; fc < 4; ++fc) {
                const int colI = ct + ch * 64 + fc * 16 + lm;
#pragma unroll
                for (int i = 0; i < 4; ++i) {
                    const float s = acc[fr][fc][i];
                    const int slot = fr * 4 + i;
                    if (s < bestV[slot]) { bestV[slot] = s; bestI[slot] = colI; }
                }
            }
#pragma unroll
        for (int fc = 0; fc < 4; ++fc) evc[fc] = evn[fc];
    }

    // cross-lane argmin over the 16 col-lanes (bits 0..3 = lm)
#pragma unroll
    for (int s = 0; s < 16; ++s) {
#pragma unroll
        for (int m = 1; m < 16; m <<= 1) {
            const float v2 = __shfl_xor(bestV[s], m);
            const int   i2 = __shfl_xor(bestI[s], m);
            if (v2 < bestV[s] || (v2 == bestV[s] && i2 < bestI[s])) {
                bestV[s] = v2; bestI[s] = i2;
            }
        }
    }
    if (lm == 0) {
#pragma unroll
        for (int s = 0; s < 16; ++s) {
            const int rl = rh * 64 + (s >> 2) * 16 + lq * 4 + (s & 3);
            RedV[rl][ch] = bestV[s]; RedI[rl][ch] = bestI[s];
        }
    }
    __syncthreads();
    if (tid < 128) {  // combine the four col-quarters; tie -> smaller index
        float v = RedV[tid][0]; int bi = RedI[tid][0];
#pragma unroll
        for (int x = 1; x < 4; ++x) {
            const float v2 = RedV[tid][x]; const int i2 = RedI[tid][x];
            if (v2 < v || (v2 == v && i2 < bi)) { v = v2; bi = i2; }
        }
        pI[rowbase + tid] = bi;
    }
}

// ---- kernel C: gather (fp32), STE out, loss partials ----
__global__ __launch_bounds__(256)
void vq_finalize(const float* __restrict__ z, const float* __restrict__ cb,
                 const int* __restrict__ pI,
                 float* __restrict__ out, float* __restrict__ bsum) {
    __shared__ float sSum[4];
    const int tid = threadIdx.x;
    const int rw = tid >> 6, lane = tid & 63;
    const int row = blockIdx.x * 4 + rw;
    const int idx = pI[row];

    const float4 zv = *(const float4*)(z  + (size_t)row * DDIM + lane * 4);
    const float4 ev = *(const float4*)(cb + (size_t)idx * DDIM + lane * 4);
    float4 d, o;
    d.x = ev.x - zv.x; d.y = ev.y - zv.y; d.z = ev.z - zv.z; d.w = ev.w - zv.w;
    o.x = zv.x + d.x;  o.y = zv.y + d.y;  o.z = zv.z + d.z;  o.w = zv.w + d.w;
    *(float4*)(out + (size_t)row * DDIM + lane * 4) = o;

    float s = d.x * d.x + d.y * d.y + d.z * d.z + d.w * d.w;
    for (int off = 32; off > 0; off >>= 1) s += __shfl_down(s, off);
    if (lane == 0) sSum[rw] = s;
    __syncthreads();
    if (tid == 0) bsum[blockIdx.x] = sSum[0] + sSum[1] + sSum[2] + sSum[3];
}

// ---- kernel D: loss ----
__global__ __launch_bounds__(256)
void loss_final(const float* __restrict__ bsum, float* __restrict__ out) {
    __shared__ float red[4];
    const int tid = threadIdx.x;
    float s = 0.f;
    for (int i = tid; i < NROWS / 4; i += 256) s += bsum[i];
    for (int off = 32; off > 0; off >>= 1) s += __shfl_down(s, off);
    const int wv = tid >> 6, lane = tid & 63;
    if (lane == 0) red[wv] = s;
    __syncthreads();
    if (tid == 0) {
        const float tot = red[0] + red[1] + red[2] + red[3];
        out[(size_t)NROWS * DDIM] = tot * (1.25f / (float)((size_t)NROWS * DDIM));
    }
}

extern "C" void kernel_launch(void* const* d_in, const int* in_sizes, int n_in,
                              void* d_out, int out_size, void* d_ws, size_t ws_size,
                              hipStream_t stream) {
    const float* z  = (const float*)d_in[0];
    const float* cb = (const float*)d_in[1];
    float* out = (float*)d_out;

    // bf16 staging inside d_out (fully overwritten by vq_finalize afterwards)
    __bf16* zbf = (__bf16*)d_out;                           // 16 MB (holds -2z)
    __bf16* cbf = (__bf16*)d_out + (size_t)NROWS * DDIM;    // 4 MB

    // workspace carve (~200 KB)
    float* esq  = (float*)d_ws;               // 8192
    int*   pI   = (int*)(esq + NCODES);       // 32768
    float* bsum = (float*)(pI + NROWS);       // 8192

    convert_bf16<<<(NROWS + NCODES) * DDIM / 8 / 256, 256, 0, stream>>>(z, cb, zbf, cbf, esq);
    vq_mfma<<<NROWS / 128, 512, 0, stream>>>(zbf, cbf, esq, pI);
    vq_finalize<<<NROWS / 4, 256, 0, stream>>>(z, cb, pI, out, bsum);
    loss_final<<<1, 256, 0, stream>>>(bsum, out);
}